// Round 4
// baseline (332.036 us; speedup 1.0000x reference)
//
#include <hip/hip_runtime.h>

// out[s,d,b, i*32 + j] = x[2s, d, b, i] + x[2s+1, d, b, j]
// x: [128,16,64,32] f32 (16 MiB), out: [64,16,64,1024] f32 (256 MiB).
//
// MEASUREMENT ROUND: kernel launched TWICE (identical dispatches, bit-exact
// same output). dur_us = C + 2X where C is the harness poison/restore
// constant; previous round gave C + X = 283.4 us. So this round's
// dur_us - 283.4 = X, the true per-dispatch kernel time.

typedef float f32x4 __attribute__((ext_vector_type(4)));

#define ROWS_TOTAL     65536   // S*D*B = 64*16*64
#define ROWS_PER_BLOCK 32
#define NBLOCKS        (ROWS_TOTAL / ROWS_PER_BLOCK)  // 2048

__global__ __launch_bounds__(256) void dense_product_kernel(
    const float* __restrict__ x, float* __restrict__ out) {
    const int bid = blockIdx.x;
    const int tid = threadIdx.x;

    const int r0    = bid * ROWS_PER_BLOCK;      // first row of this block
    const int sbase = (r0 >> 10) << 10;          // s*1024 (block-uniform)
    const int abase = (r0 + sbase) << 5;         // factor-0 flat float index

    const int i  = tid >> 3;                     // 0..31, loop-invariant
    const int j0 = (tid & 7) << 2;               // 0,4,..,28, loop-invariant

    const float* __restrict__ pa = x + abase + i;
    const float* __restrict__ pb = x + abase + 32768 + j0;
    float* __restrict__ po = out + (size_t)r0 * 1024 + tid * 4;

#pragma unroll
    for (int k = 0; k < ROWS_PER_BLOCK; ++k) {
        const float a  = pa[k * 32];
        const f32x4 bv = *reinterpret_cast<const f32x4*>(pb + k * 32);
        f32x4 o = bv + a;  // broadcast add
        __builtin_nontemporal_store(o, reinterpret_cast<f32x4*>(po + k * 1024));
    }
}

extern "C" void kernel_launch(void* const* d_in, const int* in_sizes, int n_in,
                              void* d_out, int out_size, void* d_ws, size_t ws_size,
                              hipStream_t stream) {
    const float* x   = (const float*)d_in[0];
    float*       out = (float*)d_out;
    // Two identical launches: slope probe for per-dispatch time.
    dense_product_kernel<<<NBLOCKS, 256, 0, stream>>>(x, out);
    dense_product_kernel<<<NBLOCKS, 256, 0, stream>>>(x, out);
}